// Round 3
// baseline (1995.837 us; speedup 1.0000x reference)
//
#include <hip/hip_runtime.h>
#include <math.h>

#define N_TOT 65536
#define C 512
#define HW 4096
#define M 512

// ---- ws layout (element offsets) ----
#define WS_SUMSQ 0          // 65536 f
#define WS_COLSUM 65536     // 512 f
#define WS_SMAX  66048      // 512 u32 (ordered-encoded float)
#define WS_QUT   66560      // 262144 f  (qu_T[c][m])
#define WS_F     328704     // 65536 f
#define WS_SEL   394240     // 65536 f
#define WS_GI    459776     // 65536 i32
#define WS_G2    525312     // 65536 i32
#define WS_ZERO_FLOATS 328704   // prefix that must be zeroed

// ---- d_out offsets (floats) ----
#define OUT_UQ 0L
#define OUT_UM 67108864L
#define OUT_SQ 67371008L
#define OUT_SM 100925440L
#define OUT_SEP 134479872L
#define OUT_COMP 134479873L

__device__ __forceinline__ unsigned fenc(float x){
  unsigned u = __float_as_uint(x);
  return (u & 0x80000000u) ? ~u : (u | 0x80000000u);
}
__device__ __forceinline__ float fdec(unsigned u){
  return (u & 0x80000000u) ? __uint_as_float(u & 0x7fffffffu) : __uint_as_float(~u);
}

// ---------------- K1: per-pixel sum of squares over C ----------------
__global__ __launch_bounds__(256) void k_sumsq(const float* __restrict__ q,
                                               float* __restrict__ sumsq){
  int t = threadIdx.x;
  int nchunk = blockIdx.x;   // 0..63 (1024 n each, within one b)
  int cchunk = blockIdx.y;   // 0..7  (64 c each)
  int b = nchunk >> 2;
  int hw = ((nchunk & 3) << 10) + t * 4;
  const float* base = q + ((size_t)b * C + (size_t)cchunk * 64) * HW + hw;
  float s0=0.f, s1=0.f, s2=0.f, s3=0.f;
  for (int c = 0; c < 64; c++){
    float4 v = *(const float4*)(base + (size_t)c * HW);
    s0 += v.x*v.x; s1 += v.y*v.y; s2 += v.z*v.z; s3 += v.w*v.w;
  }
  int n = (nchunk << 10) + t * 4;
  atomicAdd(&sumsq[n+0], s0);
  atomicAdd(&sumsq[n+1], s1);
  atomicAdd(&sumsq[n+2], s2);
  atomicAdd(&sumsq[n+3], s3);
}

// ---------------- K2a: score GEMM + row softmax + top2 + col stats ----------------
// block: 256 threads, 32 rows (n), all 512 cols (m). 4x4 microtile.
__global__ __launch_bounds__(256) void k_score(const float* __restrict__ q,
                                               const float* __restrict__ keys,
                                               float* __restrict__ out,
                                               float* __restrict__ ws){
  __shared__ float At[64][36];      // [k][r]
  __shared__ float Bt[64][132];     // [k][mloc]
  __shared__ float rnS[32];
  __shared__ float colsumS[512];
  __shared__ unsigned colmaxS[512];

  int t = threadIdx.x;
  int tm = t & 31, tr = t >> 5;
  int n0 = blockIdx.x * 32;
  int b = n0 >> 12, hw0 = n0 & 4095;
  const float* qb = q + (size_t)b * C * HW + hw0;
  float* uq1 = out + OUT_UQ + (size_t)b * (2*C) * HW + hw0;

  if (t < 32){
    float s = ws[WS_SUMSQ + n0 + t];
    rnS[t] = 1.0f / fmaxf(sqrtf(s), 1e-12f);
  }
  for (int i = t; i < 512; i += 256){ colsumS[i] = 0.f; colmaxS[i] = 0u; }
  __syncthreads();

  float acc[4][16];
  #pragma unroll
  for (int i = 0; i < 4; i++)
    #pragma unroll
    for (int jj = 0; jj < 16; jj++) acc[i][jj] = 0.f;

  for (int kc = 0; kc < 8; kc++){
    __syncthreads();
    { // stage A (normalized query) + write updated_query first half
      int r = t & 31, k0 = t >> 5;
      #pragma unroll
      for (int ii = 0; ii < 8; ii++){
        int k = k0 + 8*ii;
        float v = qb[(size_t)(kc*64 + k) * HW + r] * rnS[r];
        At[k][r] = v;
        uq1[(size_t)(kc*64 + k) * HW + r] = v;
      }
    }
    for (int mc = 0; mc < 4; mc++){
      if (mc) __syncthreads();
      { // stage B: keys[mc*128+mloc][kc*64+k]
        int ml0 = t >> 4;
        int k4 = (t & 15) * 4;
        #pragma unroll
        for (int ii = 0; ii < 8; ii++){
          int ml = ml0 + 16*ii;
          const float4 v = *(const float4*)&keys[(size_t)(mc*128 + ml) * C + kc*64 + k4];
          Bt[k4+0][ml] = v.x; Bt[k4+1][ml] = v.y; Bt[k4+2][ml] = v.z; Bt[k4+3][ml] = v.w;
        }
      }
      __syncthreads();
      #pragma unroll 8
      for (int k = 0; k < 64; k++){
        const float4 a  = *(const float4*)&At[k][tr*4];
        const float4 bb = *(const float4*)&Bt[k][tm*4];
        acc[0][mc*4+0] += a.x*bb.x; acc[0][mc*4+1] += a.x*bb.y; acc[0][mc*4+2] += a.x*bb.z; acc[0][mc*4+3] += a.x*bb.w;
        acc[1][mc*4+0] += a.y*bb.x; acc[1][mc*4+1] += a.y*bb.y; acc[1][mc*4+2] += a.y*bb.z; acc[1][mc*4+3] += a.y*bb.w;
        acc[2][mc*4+0] += a.z*bb.x; acc[2][mc*4+1] += a.z*bb.y; acc[2][mc*4+2] += a.z*bb.z; acc[2][mc*4+3] += a.z*bb.w;
        acc[3][mc*4+0] += a.w*bb.x; acc[3][mc*4+1] += a.w*bb.y; acc[3][mc*4+2] += a.w*bb.z; acc[3][mc*4+3] += a.w*bb.w;
      }
    }
  }

  // ---- softmax / stats (each row owned by a 32-lane group; 4 rows/thread) ----
  float rowmax[4], erm[4], rowsum[4];
  #pragma unroll
  for (int i = 0; i < 4; i++){
    float mx = acc[i][0];
    #pragma unroll
    for (int jj = 1; jj < 16; jj++) mx = fmaxf(mx, acc[i][jj]);
    #pragma unroll
    for (int off = 1; off < 32; off <<= 1) mx = fmaxf(mx, __shfl_xor(mx, off, 64));
    rowmax[i] = mx; erm[i] = __expf(mx);
  }
  // column max partials from raw scores (before overwriting acc)
  #pragma unroll
  for (int jj = 0; jj < 16; jj++){
    float cm = fmaxf(fmaxf(acc[0][jj], acc[1][jj]), fmaxf(acc[2][jj], acc[3][jj]));
    int col = (jj >> 2)*128 + tm*4 + (jj & 3);
    atomicMax(&colmaxS[col], fenc(cm));
  }
  // exponentials + row sums
  #pragma unroll
  for (int i = 0; i < 4; i++){
    float s = 0.f;
    #pragma unroll
    for (int jj = 0; jj < 16; jj++){
      float e = __expf(acc[i][jj] - rowmax[i]);
      acc[i][jj] = e; s += e;
    }
    #pragma unroll
    for (int off = 1; off < 32; off <<= 1) s += __shfl_xor(s, off, 64);
    rowsum[i] = s;
  }
  // column sum partials of raw exp(score) = e * exp(rowmax)
  #pragma unroll
  for (int jj = 0; jj < 16; jj++){
    float cp = acc[0][jj]*erm[0] + acc[1][jj]*erm[1] + acc[2][jj]*erm[2] + acc[3][jj]*erm[3];
    int col = (jj >> 2)*128 + tm*4 + (jj & 3);
    atomicAdd(&colsumS[col], cp);
  }
  // s_memory write + top-2 + per-row stats
  #pragma unroll
  for (int i = 0; i < 4; i++){
    int n = n0 + tr*4 + i;
    float rs = rowsum[i];
    float* smrow = out + OUT_SM + (size_t)n * 512;
    #pragma unroll
    for (int mc = 0; mc < 4; mc++){
      float4 v = make_float4(acc[i][mc*4+0]/rs, acc[i][mc*4+1]/rs,
                             acc[i][mc*4+2]/rs, acc[i][mc*4+3]/rs);
      *(float4*)&smrow[mc*128 + tm*4] = v;
    }
    float v1 = -1e30f, v2 = -1e30f; int i1 = 0x7fffffff, i2 = 0x7fffffff;
    #pragma unroll
    for (int jj = 0; jj < 16; jj++){
      float v = acc[i][jj]; int ci = (jj >> 2)*128 + tm*4 + (jj & 3);
      if (v > v1 || (v == v1 && ci < i1)) { v2 = v1; i2 = i1; v1 = v; i1 = ci; }
      else if (v > v2 || (v == v2 && ci < i2)) { v2 = v; i2 = ci; }
    }
    #pragma unroll
    for (int off = 1; off < 32; off <<= 1){
      float ov1 = __shfl_xor(v1, off, 64); int oi1 = __shfl_xor(i1, off, 64);
      float ov2 = __shfl_xor(v2, off, 64); int oi2 = __shfl_xor(i2, off, 64);
      bool takeO = (ov1 > v1) || (ov1 == v1 && oi1 < i1);
      float nv1 = takeO ? ov1 : v1; int ni1 = takeO ? oi1 : i1;
      float lv  = takeO ? v1 : ov1; int li  = takeO ? i1 : oi1;
      float wv2 = takeO ? ov2 : v2; int wi2 = takeO ? oi2 : i2;
      bool t2b = (wv2 > lv) || (wv2 == lv && wi2 < li);
      v1 = nv1; i1 = ni1;
      v2 = t2b ? wv2 : lv; i2 = t2b ? wi2 : li;
    }
    if (tm == 0){
      ws[WS_F + n]   = rowsum[i] * erm[i];     // rowsum * exp(rowmax)
      ws[WS_SEL + n] = rowmax[i];              // score at top-1 == rowmax
      ((int*)ws)[WS_GI + n] = i1;
      ((int*)ws)[WS_G2 + n] = i2;
    }
  }
  __syncthreads();
  for (int i = t; i < 512; i += 256){
    atomicAdd(&ws[WS_COLSUM + i], colsumS[i]);
    atomicMax(&((unsigned*)ws)[WS_SMAX + i], colmaxS[i]);
  }
}

// ---------------- K2b: concat = s_memory @ keys, written transposed into updated_query ----------------
__global__ __launch_bounds__(256) void k_concat(const float* __restrict__ keys,
                                                const float* __restrict__ sm,
                                                float* __restrict__ out){
  __shared__ float At[64][36];     // [m~][r]
  __shared__ float Bt[64][132];    // [m~][cl]
  __shared__ float T[32][133];     // transpose staging for output

  int t = threadIdx.x;
  int tm = t & 31, tr = t >> 5;
  int n0 = blockIdx.x * 32;
  int b = n0 >> 12, hw0 = n0 & 4095;

  float acc[4][16];
  #pragma unroll
  for (int i = 0; i < 4; i++)
    #pragma unroll
    for (int jj = 0; jj < 16; jj++) acc[i][jj] = 0.f;

  for (int kc = 0; kc < 8; kc++){   // K dim = m
    __syncthreads();
    { // stage A = s_memory rows (transposed into [m~][r])
      int r0 = t >> 4;
      int k4 = (t & 15) * 4;
      #pragma unroll
      for (int ii = 0; ii < 2; ii++){
        int rr = r0 + 16*ii;
        const float4 v = *(const float4*)&sm[(size_t)(n0 + rr) * 512 + kc*64 + k4];
        At[k4+0][rr] = v.x; At[k4+1][rr] = v.y; At[k4+2][rr] = v.z; At[k4+3][rr] = v.w;
      }
    }
    for (int cc = 0; cc < 4; cc++){
      if (cc) __syncthreads();
      { // stage B = keys[kc*64+mrow][cc*128 + c]
        int mrow0 = t >> 5;
        int c4 = (t & 31) * 4;
        #pragma unroll
        for (int ii = 0; ii < 8; ii++){
          int mrow = mrow0 + 8*ii;
          const float4 v = *(const float4*)&keys[(size_t)(kc*64 + mrow) * 512 + cc*128 + c4];
          *(float4*)&Bt[mrow][c4] = v;
        }
      }
      __syncthreads();
      #pragma unroll 8
      for (int k = 0; k < 64; k++){
        const float4 a  = *(const float4*)&At[k][tr*4];
        const float4 bb = *(const float4*)&Bt[k][tm*4];
        acc[0][cc*4+0] += a.x*bb.x; acc[0][cc*4+1] += a.x*bb.y; acc[0][cc*4+2] += a.x*bb.z; acc[0][cc*4+3] += a.x*bb.w;
        acc[1][cc*4+0] += a.y*bb.x; acc[1][cc*4+1] += a.y*bb.y; acc[1][cc*4+2] += a.y*bb.z; acc[1][cc*4+3] += a.y*bb.w;
        acc[2][cc*4+0] += a.z*bb.x; acc[2][cc*4+1] += a.z*bb.y; acc[2][cc*4+2] += a.z*bb.z; acc[2][cc*4+3] += a.z*bb.w;
        acc[3][cc*4+0] += a.w*bb.x; acc[3][cc*4+1] += a.w*bb.y; acc[3][cc*4+2] += a.w*bb.z; acc[3][cc*4+3] += a.w*bb.w;
      }
    }
  }
  // epilogue: transpose each 32x128 chunk through LDS, write (c, hw)-major
  for (int cc = 0; cc < 4; cc++){
    __syncthreads();
    #pragma unroll
    for (int i = 0; i < 4; i++)
      #pragma unroll
      for (int j = 0; j < 4; j++)
        T[tr*4+i][tm*4+j] = acc[i][cc*4+j];
    __syncthreads();
    int hw = t & 31;
    int cl0 = t >> 5;
    #pragma unroll
    for (int ii = 0; ii < 16; ii++){
      int cl = cl0 + 8*ii;
      out[OUT_UQ + ((size_t)b*1024 + 512 + cc*128 + cl) * HW + hw0 + hw] = T[hw][cl];
    }
  }
}

// ---------------- K3: losses ----------------
__global__ __launch_bounds__(256) void k_loss(const float* __restrict__ keys,
                                              const float* __restrict__ uq,
                                              const int* __restrict__ gi,
                                              const int* __restrict__ g2,
                                              float* __restrict__ out){
  __shared__ float kS[512][9];
  __shared__ float redS[8];
  int t = threadIdx.x;
  int n = blockIdx.x * 256 + t;
  int b = n >> 12, hw = n & 4095;
  const float* qb = uq + (size_t)b * 1024 * HW + hw;
  int p = gi[n], sx = g2[n];
  float comp = 0.f, dp = 0.f, dn = 0.f;
  for (int c0 = 0; c0 < 512; c0 += 8){
    __syncthreads();
    {
      int m0 = t * 2;
      #pragma unroll
      for (int i = 0; i < 2; i++){
        const float* kr = &keys[(size_t)(m0 + i) * 512 + c0];
        #pragma unroll
        for (int j = 0; j < 8; j++) kS[m0 + i][j] = kr[j];
      }
    }
    __syncthreads();
    #pragma unroll
    for (int cc = 0; cc < 8; cc++){
      float qv = qb[(size_t)(c0 + cc) * HW];
      float d  = qv - kS[p][cc];  comp += d*d;
      float e1 = d + 1e-6f;       dp += e1*e1;
      float e2 = qv - kS[sx][cc] + 1e-6f; dn += e2*e2;
    }
  }
  float sep = fmaxf(sqrtf(dp) - sqrtf(dn) + 1.0f, 0.0f);
  #pragma unroll
  for (int off = 32; off; off >>= 1){
    comp += __shfl_down(comp, off, 64);
    sep  += __shfl_down(sep, off, 64);
  }
  if ((t & 63) == 0){ redS[t >> 6] = comp; redS[4 + (t >> 6)] = sep; }
  __syncthreads();
  if (t == 0){
    float ctot = redS[0] + redS[1] + redS[2] + redS[3];
    float stot = redS[4] + redS[5] + redS[6] + redS[7];
    atomicAdd(&out[OUT_COMP], ctot * (1.0f / ((float)N_TOT * (float)C)));
    atomicAdd(&out[OUT_SEP],  stot * (1.0f / (float)N_TOT));
  }
}

// ---------------- K4: s_query = s_memory * f[n] / colsum[m] ----------------
__global__ __launch_bounds__(256) void k_squery(const float* __restrict__ sm,
                                                const float* __restrict__ f,
                                                const float* __restrict__ colsum,
                                                float* __restrict__ sq){
  size_t idx4 = ((size_t)blockIdx.x * 256 + threadIdx.x) * 4;
  int n = (int)(idx4 >> 9);
  int m = (int)(idx4 & 511);
  float4 v = *(const float4*)&sm[idx4];
  const float4 cs = *(const float4*)&colsum[m];
  float fv = f[n];
  v.x = v.x * fv / cs.x;
  v.y = v.y * fv / cs.y;
  v.z = v.z * fv / cs.z;
  v.w = v.w * fv / cs.w;
  *(float4*)&sq[idx4] = v;
}

// ---------------- K5: transposed segment sum: qu_T[c][m] = sum_n w[n]*qr[n][c] [gi==m] ----------------
__global__ __launch_bounds__(256) void k_segsum(const float* __restrict__ uq,
                                                const int* __restrict__ gi,
                                                const float* __restrict__ sel,
                                                const unsigned* __restrict__ smax_enc,
                                                float* __restrict__ quT){
  __shared__ float bins[512];
  __shared__ float smaxS[512];
  int t = threadIdx.x;
  int c = blockIdx.x;
  for (int i = t; i < 512; i += 256){ bins[i] = 0.f; smaxS[i] = fdec(smax_enc[i]); }
  __syncthreads();
  for (int n0 = 0; n0 < N_TOT; n0 += 256){
    int n = n0 + t;
    int g = gi[n];
    float w = __expf(sel[n] - smaxS[g]);
    int b = n >> 12, hw = n & 4095;
    float val = uq[((size_t)b * 1024 + c) * HW + hw];
    atomicAdd(&bins[g], w * val);
  }
  __syncthreads();
  for (int i = t; i < 512; i += 256) quT[(size_t)c * 512 + i] = bins[i];
}

// ---------------- K6: updated_memory = l2norm(qu + keys) ----------------
__global__ __launch_bounds__(256) void k_upmem(const float* __restrict__ quT,
                                               const float* __restrict__ keys,
                                               float* __restrict__ um){
  __shared__ float partial[4];
  int t = threadIdx.x;
  int m = blockIdx.x;
  float va = quT[(size_t)t * 512 + m]        + keys[(size_t)m * 512 + t];
  float vb = quT[(size_t)(t + 256) * 512 + m] + keys[(size_t)m * 512 + t + 256];
  float s = va*va + vb*vb;
  #pragma unroll
  for (int off = 1; off < 64; off <<= 1) s += __shfl_xor(s, off, 64);
  if ((t & 63) == 0) partial[t >> 6] = s;
  __syncthreads();
  float tot = partial[0] + partial[1] + partial[2] + partial[3];
  float rn = 1.0f / fmaxf(sqrtf(tot), 1e-12f);
  um[(size_t)m * 512 + t] = va * rn;
  um[(size_t)m * 512 + t + 256] = vb * rn;
}

extern "C" void kernel_launch(void* const* d_in, const int* in_sizes, int n_in,
                              void* d_out, int out_size, void* d_ws, size_t ws_size,
                              hipStream_t stream) {
  (void)in_sizes; (void)n_in; (void)out_size; (void)ws_size;
  const float* q    = (const float*)d_in[0];
  const float* keys = (const float*)d_in[1];
  float* out = (float*)d_out;
  float* ws  = (float*)d_ws;

  hipMemsetAsync(d_ws, 0, (size_t)WS_ZERO_FLOATS * 4, stream);
  hipMemsetAsync((char*)d_out + (size_t)OUT_SEP * 4, 0, 8, stream);

  k_sumsq <<<dim3(64, 8), 256, 0, stream>>>(q, ws + WS_SUMSQ);
  k_score <<<2048, 256, 0, stream>>>(q, keys, out, ws);
  k_concat<<<2048, 256, 0, stream>>>(keys, out + OUT_SM, out);
  k_loss  <<<256, 256, 0, stream>>>(keys, out, (const int*)ws + WS_GI, (const int*)ws + WS_G2, out);
  k_squery<<<32768, 256, 0, stream>>>(out + OUT_SM, ws + WS_F, ws + WS_COLSUM, out + OUT_SQ);
  k_segsum<<<512, 256, 0, stream>>>(out, (const int*)ws + WS_GI, ws + WS_SEL,
                                    (const unsigned*)ws + WS_SMAX, ws + WS_QUT);
  k_upmem <<<512, 256, 0, stream>>>(ws + WS_QUT, keys, out + OUT_UM);
}